// Round 2
// 1905.650 us; speedup vs baseline: 1.0046x; 1.0046x over previous
//
#include <hip/hip_runtime.h>

// PrototypeNetwork: per-class prototypes from cosine-similarity row-means.
//   u = f/max(||f||,eps); m[c] = seg_sum(u); n_c = counts;
//   w_i = (u_i.m[lab_i] - u_i.u_i) / (max(n_c-1,1)*max(n_c,1)*max(n_c,1));
//   out[c] = seg_sum(w_i * f_i)   (final /n_c folded into w).
//
// R3/R4: the R2 kernel's end-of-block flush was 9.8M device-scope atomicAdds
// (768-way contention on 12800 addresses) -> memory-side RMW write-through
// (WRITE_SIZE 83.5 MB vs 51 KB logical). Replaced with per-block partial
// stores (39.7 MB coalesced) + split-P reduction kernels. BLOCK 256->512
// lifts occupancy 12 -> 24 waves/CU for the latency-bound loop. R4 = R3 with
// the __launch_bounds__ min-waves clause dropped (bench infra failed on R3;
// removing the only discretionary launch-config risk before retry).

namespace {

constexpr int C = 100;
constexpr int D = 128;
constexpr float EPS = 1e-8f;
constexpr int BLOCK = 512;        // 8 waves; 3 blocks/CU (LDS-limited) = 24 waves/CU
constexpr int GRID = 768;         // 3 blocks/CU * 256 CU, all resident
constexpr int S = 8;              // samples per wave per iteration (2 per sub-step)
constexpr int SLOT_F = C * D + 128;  // 12928 floats/slot: m (12800) | cnt (100) | pad
constexpr int RED_SPLIT = 8;      // reduction split across slot ranges

__global__ __launch_bounds__(BLOCK) void k_stats(const float4* __restrict__ feat4,
                                                 const int* __restrict__ lab,
                                                 float* __restrict__ partial,
                                                 float* __restrict__ mcnt_g,
                                                 int n, int mode) {
  // Permuted LDS layout: index class*128 + q*32 + sl  <->  dim d = 4*sl + q.
  __shared__ float m_loc[C * D];
  __shared__ float cnt_loc[C];
  for (int i = threadIdx.x; i < C * D; i += BLOCK) m_loc[i] = 0.f;
  if (threadIdx.x < C) cnt_loc[threadIdx.x] = 0.f;
  __syncthreads();

  const int lane = threadIdx.x & 63;
  const int half = lane >> 5;   // which of 2 samples per sub-step
  const int sl = lane & 31;     // lane within half: owns dims 4*sl..4*sl+3
  const int wid = (blockIdx.x * BLOCK + threadIdx.x) >> 6;
  const int nw = (GRID * BLOCK) >> 6;

  for (int base = wid * S; base < n; base += nw * S) {
    float4 x[4];
    int c[4];
    bool valid[4];
#pragma unroll
    for (int s = 0; s < 4; ++s) {
      int idx = base + 2 * s + half;
      valid[s] = idx < n;
      int ci = valid[s] ? idx : n - 1;  // clamped load, accumulate skipped
      x[s] = feat4[(size_t)ci * 32 + sl];
      c[s] = lab[ci];
    }
    float ss[4];
#pragma unroll
    for (int s = 0; s < 4; ++s)
      ss[s] = x[s].x * x[s].x + x[s].y * x[s].y + x[s].z * x[s].z + x[s].w * x[s].w;
#pragma unroll
    for (int off = 16; off > 0; off >>= 1) {
#pragma unroll
      for (int s = 0; s < 4; ++s) ss[s] += __shfl_xor(ss[s], off, 64);
    }
#pragma unroll
    for (int s = 0; s < 4; ++s) {
      if (!valid[s]) continue;
      float inv = 1.0f / fmaxf(sqrtf(ss[s]), EPS);
      float* mp = &m_loc[c[s] * D];
      atomicAdd(&mp[0 * 32 + sl], x[s].x * inv);
      atomicAdd(&mp[1 * 32 + sl], x[s].y * inv);
      atomicAdd(&mp[2 * 32 + sl], x[s].z * inv);
      atomicAdd(&mp[3 * 32 + sl], x[s].w * inv);
      if (sl == 0) atomicAdd(&cnt_loc[c[s]], 1.0f);
    }
  }
  __syncthreads();

  if (mode) {
    // Plain coalesced stores to this block's private slot (unpermute to natural).
    float* slot = partial + (size_t)blockIdx.x * SLOT_F;
    for (int i = threadIdx.x; i < C * D; i += BLOCK) {
      int cls = i >> 7, a = i & 127, q = a >> 5, s2 = a & 31;
      slot[cls * D + s2 * 4 + q] = m_loc[i];
    }
    for (int i = threadIdx.x; i < SLOT_F - C * D; i += BLOCK)
      slot[C * D + i] = (i < C) ? cnt_loc[i] : 0.f;
  } else {
    // Fallback (tiny ws): contended device atomics, as in R2.
    for (int i = threadIdx.x; i < C * D; i += BLOCK) {
      int cls = i >> 7, a = i & 127, q = a >> 5, s2 = a & 31;
      atomicAdd(&mcnt_g[cls * D + s2 * 4 + q], m_loc[i]);
    }
    if (threadIdx.x < C) atomicAdd(&mcnt_g[C * D + threadIdx.x], cnt_loc[threadIdx.x]);
  }
}

__global__ __launch_bounds__(BLOCK) void k_proto(const float4* __restrict__ feat4,
                                                 const int* __restrict__ lab,
                                                 const float4* __restrict__ m_g4,
                                                 const float* __restrict__ cnt_g,
                                                 float* __restrict__ partial,
                                                 float* __restrict__ out,
                                                 int n, int mode) {
  __shared__ float p_loc[C * D];  // permuted layout, same as k_stats
  __shared__ float cnt_loc[C];
  for (int i = threadIdx.x; i < C * D; i += BLOCK) p_loc[i] = 0.f;
  if (threadIdx.x < C) cnt_loc[threadIdx.x] = cnt_g[threadIdx.x];
  __syncthreads();

  const int lane = threadIdx.x & 63;
  const int half = lane >> 5;
  const int sl = lane & 31;
  const int wid = (blockIdx.x * BLOCK + threadIdx.x) >> 6;
  const int nw = (GRID * BLOCK) >> 6;

  for (int base = wid * S; base < n; base += nw * S) {
    float4 x[4], mv[4];
    int c[4];
    bool valid[4];
#pragma unroll
    for (int s = 0; s < 4; ++s) {
      int idx = base + 2 * s + half;
      valid[s] = idx < n;
      int ci = valid[s] ? idx : n - 1;
      x[s] = feat4[(size_t)ci * 32 + sl];
      c[s] = lab[ci];
    }
#pragma unroll
    for (int s = 0; s < 4; ++s) mv[s] = m_g4[c[s] * 32 + sl];  // 50 KB, L1/L2-hot

    float ss[4], pm[4];
#pragma unroll
    for (int s = 0; s < 4; ++s) {
      ss[s] = x[s].x * x[s].x + x[s].y * x[s].y + x[s].z * x[s].z + x[s].w * x[s].w;
      pm[s] = x[s].x * mv[s].x + x[s].y * mv[s].y + x[s].z * mv[s].z + x[s].w * mv[s].w;
    }
#pragma unroll
    for (int off = 16; off > 0; off >>= 1) {
#pragma unroll
      for (int s = 0; s < 4; ++s) {
        ss[s] += __shfl_xor(ss[s], off, 64);
        pm[s] += __shfl_xor(pm[s], off, 64);
      }
    }
#pragma unroll
    for (int s = 0; s < 4; ++s) {
      if (!valid[s]) continue;
      float inv = 1.0f / fmaxf(sqrtf(ss[s]), EPS);
      float row_sum = pm[s] * inv - ss[s] * inv * inv;  // u.m - u.u (f==0 safe)
      float nc = cnt_loc[c[s]];
      // denom includes the final /max(nc,1) so the reduction writes out directly.
      float w = row_sum / (fmaxf(nc - 1.f, 1.f) * fmaxf(nc, 1.f) * fmaxf(nc, 1.f));
      float* pp = &p_loc[c[s] * D];
      atomicAdd(&pp[0 * 32 + sl], w * x[s].x);
      atomicAdd(&pp[1 * 32 + sl], w * x[s].y);
      atomicAdd(&pp[2 * 32 + sl], w * x[s].z);
      atomicAdd(&pp[3 * 32 + sl], w * x[s].w);
    }
  }
  __syncthreads();

  if (mode) {
    float* slot = partial + (size_t)blockIdx.x * SLOT_F;
    for (int i = threadIdx.x; i < C * D; i += BLOCK) {
      int cls = i >> 7, a = i & 127, q = a >> 5, s2 = a & 31;
      slot[cls * D + s2 * 4 + q] = p_loc[i];
    }
  } else {
    for (int i = threadIdx.x; i < C * D; i += BLOCK) {
      int cls = i >> 7, a = i & 127, q = a >> 5, s2 = a & 31;
      atomicAdd(&out[cls * D + s2 * 4 + q], p_loc[i]);
    }
  }
}

// Sum `nslots` partial slots elementwise into dst (split across gridDim.y ranges;
// 8-way atomic contention max -- negligible).
__global__ void k_reduce(const float* __restrict__ partial, float* __restrict__ dst,
                         int width, int stride, int nslots) {
  int i = blockIdx.x * blockDim.x + threadIdx.x;
  if (i >= width) return;
  int chunk = (nslots + gridDim.y - 1) / gridDim.y;
  int p0 = blockIdx.y * chunk;
  int p1 = p0 + chunk;
  if (p1 > nslots) p1 = nslots;
  float acc = 0.f;
#pragma unroll 8
  for (int p = p0; p < p1; ++p) acc += partial[(size_t)p * stride + i];
  atomicAdd(&dst[i], acc);
}

}  // namespace

extern "C" void kernel_launch(void* const* d_in, const int* in_sizes, int n_in,
                              void* d_out, int out_size, void* d_ws, size_t ws_size,
                              hipStream_t stream) {
  const float* feat = (const float*)d_in[0];
  const int* lab = (const int*)d_in[1];
  const int n = in_sizes[0] / D;

  // ws layout: mcnt[SLOT_F] (m[C*D] | cnt[C] | pad) | partial[GRID][SLOT_F]
  float* mcnt = (float*)d_ws;
  float* partial = mcnt + SLOT_F;
  const size_t need = (size_t)(GRID + 1) * SLOT_F * sizeof(float);
  const int mode = (ws_size >= need) ? 1 : 0;

  hipMemsetAsync(mcnt, 0, SLOT_F * sizeof(float), stream);
  hipMemsetAsync(d_out, 0, out_size, stream);

  k_stats<<<GRID, BLOCK, 0, stream>>>((const float4*)feat, lab, partial, mcnt, n, mode);
  if (mode)
    k_reduce<<<dim3((SLOT_F + 255) / 256, RED_SPLIT), 256, 0, stream>>>(
        partial, mcnt, SLOT_F, SLOT_F, GRID);

  k_proto<<<GRID, BLOCK, 0, stream>>>((const float4*)feat, lab, (const float4*)mcnt,
                                      mcnt + C * D, partial, (float*)d_out, n, mode);
  if (mode)
    k_reduce<<<dim3((C * D + 255) / 256, RED_SPLIT), 256, 0, stream>>>(
        partial, (float*)d_out, C * D, SLOT_F, GRID);
}